// Round 1
// baseline (939.290 us; speedup 1.0000x reference)
//
#include <hip/hip_runtime.h>
#include <stdint.h>

#define HIDDEN 1024
#define INTER  4096
#define NTOK   4096
#define HROWS  (2*NTOK)
#define BM     128
#define BN     128
#define BK     64
#define MAXBLK 72

typedef unsigned short u16;
typedef unsigned int   u32;
typedef __bf16  bf16x8 __attribute__((ext_vector_type(8)));
typedef float   f32x4  __attribute__((ext_vector_type(4)));
typedef u32     u32x4  __attribute__((ext_vector_type(4)));

#define COMP(vec, i) ((i)==0 ? (vec).x : (i)==1 ? (vec).y : (i)==2 ? (vec).z : (vec).w)

__device__ __forceinline__ u16 f2bf(float f) {
  u32 u = __float_as_uint(f);
  u32 r = u + 0x7FFFu + ((u >> 16) & 1u);
  return (u16)(r >> 16);
}

__device__ __forceinline__ u32 cvt_pk_bf16(float lo, float hi) {
  u32 r;
  asm("v_cvt_pk_bf16_f32 %0, %1, %2" : "=v"(r) : "v"(lo), "v"(hi));
  return r;
}

__device__ __forceinline__ void glds16(const void* g, void* l) {
  __builtin_amdgcn_global_load_lds(
      (const __attribute__((address_space(1))) void*)g,
      (__attribute__((address_space(3))) void*)l, 16, 0, 0);
}

// ---------------- routing ----------------

__global__ void k_init(int* cnt, int* fill) {
  if (threadIdx.x < 8) { cnt[threadIdx.x] = 0; fill[threadIdx.x] = 0; }
}

__global__ __launch_bounds__(256) void k_gate(const float* __restrict__ x,
                                              const float* __restrict__ wg,
                                              int* __restrict__ idx,
                                              int* __restrict__ cnt) {
  int wave = threadIdx.x >> 6, lane = threadIdx.x & 63;
  int t = blockIdx.x * 4 + wave;
  if (t >= NTOK) return;
  float acc[8];
  #pragma unroll
  for (int e = 0; e < 8; ++e) acc[e] = 0.f;
  const float* xr = x + (size_t)t * HIDDEN;
  for (int c = lane; c < HIDDEN; c += 64) {
    float xv = xr[c];
    const float* wrow = wg + (size_t)c * 8;
    #pragma unroll
    for (int e = 0; e < 8; ++e) acc[e] += xv * wrow[e];
  }
  #pragma unroll
  for (int e = 0; e < 8; ++e)
    for (int s = 32; s; s >>= 1) acc[e] += __shfl_xor(acc[e], s);
  if (lane == 0) {
    int best = 0; float bv = acc[0];
    #pragma unroll
    for (int e = 1; e < 8; ++e) if (acc[e] > bv) { bv = acc[e]; best = e; }
    idx[t] = best;
    atomicAdd(&cnt[best], 1);
  }
}

__global__ void k_cvt(const float* __restrict__ x, u16* __restrict__ xb, int n4) {
  int i = blockIdx.x * blockDim.x + threadIdx.x;
  if (i >= n4) return;
  float4 v = ((const float4*)x)[i];
  u32x4 dummy; (void)dummy;
  ushort4 o;
  o.x = f2bf(v.x); o.y = f2bf(v.y); o.z = f2bf(v.z); o.w = f2bf(v.w);
  ((ushort4*)xb)[i] = o;
}

__global__ void k_table(const int* __restrict__ cnt, int* __restrict__ off,
                        int4* __restrict__ tab, int* __restrict__ nblk) {
  if (threadIdx.x != 0 || blockIdx.x != 0) return;
  int o = 0, nb = 0;
  int offs[8];
  for (int e = 0; e < 8; ++e) { offs[e] = o; off[e] = o; o += cnt[e]; }
  for (int m = 0; m < NTOK / BM; ++m)
    tab[nb++] = make_int4(8, m * BM, BM, 0);
  for (int e = 0; e < 8; ++e) {
    for (int j = 0; j * BM < cnt[e]; ++j) {
      int rows = cnt[e] - j * BM; if (rows > BM) rows = BM;
      tab[nb++] = make_int4(e, NTOK + offs[e] + j * BM, rows, offs[e] + j * BM);
    }
  }
  *nblk = nb;
}

__global__ void k_scatter(const int* __restrict__ idx, const int* __restrict__ off,
                          int* __restrict__ fill, int* __restrict__ perm) {
  int t = blockIdx.x * blockDim.x + threadIdx.x;
  if (t >= NTOK) return;
  int e = idx[t];
  int p = atomicAdd(&fill[e], 1);
  perm[off[e] + p] = t;
}

// ---------------- B staging: fp32 [K][N] global -> bf16 [N][K] LDS (swizzled) ----------------

__device__ __forceinline__ void stage_b(const float* __restrict__ B, u16* lB,
                                        int k0, int nbase, int ku, int n0, int ldw) {
  const float* p = B + (size_t)(k0 + ku * 8) * ldw + nbase + n0;
  float4 v[8];
  #pragma unroll
  for (int dk = 0; dk < 8; ++dk) v[dk] = *(const float4*)(p + (size_t)dk * ldw);
  #pragma unroll
  for (int dn = 0; dn < 4; ++dn) {
    int n = n0 + dn;
    u32x4 pk;
    pk.x = cvt_pk_bf16(COMP(v[0], dn), COMP(v[1], dn));
    pk.y = cvt_pk_bf16(COMP(v[2], dn), COMP(v[3], dn));
    pk.z = cvt_pk_bf16(COMP(v[4], dn), COMP(v[5], dn));
    pk.w = cvt_pk_bf16(COMP(v[6], dn), COMP(v[7], dn));
    *(u32x4*)&lB[n * BK + ((ku ^ (n & 7)) * 8)] = pk;
  }
}

// ---------------- stage 1: H = gelu(Xg@W1) * (Xg@W2), bf16 ----------------

__global__ __launch_bounds__(256) void k_mlp1(
    const u16* __restrict__ xb,
    const float* __restrict__ w1s, const float* __restrict__ w2s,
    const float* __restrict__ W1,  const float* __restrict__ W2,
    const int* __restrict__ perm, const int4* __restrict__ tab,
    const int* __restrict__ nblk, u16* __restrict__ Hbuf)
{
  int bx = blockIdx.x;
  if (bx >= *nblk) return;
  int4 te = tab[bx];
  int g = te.x, hrow0 = te.y, rows = te.z, pb = te.w;
  const float* B1 = (g == 8) ? w1s : (W1 + (size_t)g * HIDDEN * INTER);
  const float* B2 = (g == 8) ? w2s : (W2 + (size_t)g * HIDDEN * INTER);
  int nbase = blockIdx.y * BN;

  int tid = threadIdx.x;
  int w = tid >> 6, lane = tid & 63;
  int q = lane >> 4, rl = lane & 15;
  int wr = (w >> 1) * 64, wc = (w & 1) * 64;

  __shared__ __align__(16) u16 lA[BM * BK];
  __shared__ __align__(16) u16 lB1[BN * BK];
  __shared__ __align__(16) u16 lB2[BN * BK];

  int tokj[4];
  #pragma unroll
  for (int j = 0; j < 4; ++j) {
    int r = w * 32 + j * 8 + (lane >> 3);
    int rc = (r < rows) ? r : (rows - 1);
    tokj[j] = (g == 8) ? (hrow0 + rc) : perm[pb + rc];
  }
  int schunk = (lane & 7) ^ ((lane >> 3) & 7);
  int ku = tid & 7;
  int n0 = (tid >> 3) * 4;

  f32x4 acc1[4][4], acc2[4][4];
  f32x4 z = {0.f, 0.f, 0.f, 0.f};
  #pragma unroll
  for (int mi = 0; mi < 4; ++mi)
    #pragma unroll
    for (int ni = 0; ni < 4; ++ni) { acc1[mi][ni] = z; acc2[mi][ni] = z; }

  for (int kt = 0; kt < HIDDEN / BK; ++kt) {
    int k0 = kt * BK;
    #pragma unroll
    for (int j = 0; j < 4; ++j) {
      const char* src = (const char*)xb + ((size_t)tokj[j] * HIDDEN + k0) * 2 + schunk * 16;
      glds16(src, (char*)lA + w * 4096 + j * 1024);
    }
    stage_b(B1, lB1, k0, nbase, ku, n0, INTER);
    stage_b(B2, lB2, k0, nbase, ku, n0, INTER);
    __syncthreads();
    #pragma unroll
    for (int ks = 0; ks < 2; ++ks) {
      int co = (((ks << 2) | q) ^ (rl & 7)) * 8;
      bf16x8 af[4], bf1[4], bf2[4];
      #pragma unroll
      for (int mi = 0; mi < 4; ++mi) {
        int r = wr + mi * 16 + rl;
        af[mi] = *(const bf16x8*)&lA[r * BK + co];
      }
      #pragma unroll
      for (int ni = 0; ni < 4; ++ni) {
        int n = wc + ni * 16 + rl;
        bf1[ni] = *(const bf16x8*)&lB1[n * BK + co];
        bf2[ni] = *(const bf16x8*)&lB2[n * BK + co];
      }
      #pragma unroll
      for (int mi = 0; mi < 4; ++mi)
        #pragma unroll
        for (int ni = 0; ni < 4; ++ni) {
          acc1[mi][ni] = __builtin_amdgcn_mfma_f32_16x16x32_bf16(af[mi], bf1[ni], acc1[mi][ni], 0, 0, 0);
          acc2[mi][ni] = __builtin_amdgcn_mfma_f32_16x16x32_bf16(af[mi], bf2[ni], acc2[mi][ni], 0, 0, 0);
        }
    }
    __syncthreads();
  }

  #pragma unroll
  for (int mi = 0; mi < 4; ++mi) {
    #pragma unroll
    for (int j = 0; j < 4; ++j) {
      int r = wr + mi * 16 + q * 4 + j;
      if (r < rows) {
        size_t hb = (size_t)(hrow0 + r) * INTER + nbase + wc;
        #pragma unroll
        for (int ni = 0; ni < 4; ++ni) {
          float h1 = acc1[mi][ni][j];
          float h2 = acc2[mi][ni][j];
          float ge = 0.5f * h1 * (1.0f + erff(h1 * 0.7071067811865476f));
          Hbuf[hb + ni * 16 + rl] = f2bf(ge * h2);
        }
      }
    }
  }
}

// ---------------- stage 2: Y = H @ W3 ----------------

__global__ __launch_bounds__(256) void k_mlp2(
    const u16* __restrict__ Hbuf, const float* __restrict__ w3s,
    const float* __restrict__ W3, const int* __restrict__ perm,
    const int4* __restrict__ tab, const int* __restrict__ nblk,
    float* __restrict__ out, float* __restrict__ yexp)
{
  int bx = blockIdx.x;
  if (bx >= *nblk) return;
  int4 te = tab[bx];
  int g = te.x, hrow0 = te.y, rows = te.z, pb = te.w;
  const float* B3 = (g == 8) ? w3s : (W3 + (size_t)g * INTER * HIDDEN);
  int nbase = blockIdx.y * BN;

  int tid = threadIdx.x;
  int w = tid >> 6, lane = tid & 63;
  int q = lane >> 4, rl = lane & 15;
  int wr = (w >> 1) * 64, wc = (w & 1) * 64;

  __shared__ __align__(16) u16 lA[BM * BK];
  __shared__ __align__(16) u16 lB[BN * BK];

  int hr[4];
  #pragma unroll
  for (int j = 0; j < 4; ++j) {
    int r = hrow0 + w * 32 + j * 8 + (lane >> 3);
    hr[j] = (r < HROWS) ? r : (HROWS - 1);
  }
  int schunk = (lane & 7) ^ ((lane >> 3) & 7);
  int ku = tid & 7;
  int n0 = (tid >> 3) * 4;

  f32x4 acc[4][4];
  f32x4 z = {0.f, 0.f, 0.f, 0.f};
  #pragma unroll
  for (int mi = 0; mi < 4; ++mi)
    #pragma unroll
    for (int ni = 0; ni < 4; ++ni) acc[mi][ni] = z;

  for (int kt = 0; kt < INTER / BK; ++kt) {
    int k0 = kt * BK;
    #pragma unroll
    for (int j = 0; j < 4; ++j) {
      const char* src = (const char*)Hbuf + ((size_t)hr[j] * INTER + k0) * 2 + schunk * 16;
      glds16(src, (char*)lA + w * 4096 + j * 1024);
    }
    stage_b(B3, lB, k0, nbase, ku, n0, HIDDEN);
    __syncthreads();
    #pragma unroll
    for (int ks = 0; ks < 2; ++ks) {
      int co = (((ks << 2) | q) ^ (rl & 7)) * 8;
      bf16x8 af[4], bf[4];
      #pragma unroll
      for (int mi = 0; mi < 4; ++mi) {
        int r = wr + mi * 16 + rl;
        af[mi] = *(const bf16x8*)&lA[r * BK + co];
      }
      #pragma unroll
      for (int ni = 0; ni < 4; ++ni) {
        int n = wc + ni * 16 + rl;
        bf[ni] = *(const bf16x8*)&lB[n * BK + co];
      }
      #pragma unroll
      for (int mi = 0; mi < 4; ++mi)
        #pragma unroll
        for (int ni = 0; ni < 4; ++ni)
          acc[mi][ni] = __builtin_amdgcn_mfma_f32_16x16x32_bf16(af[mi], bf[ni], acc[mi][ni], 0, 0, 0);
    }
    __syncthreads();
  }

  float* dstb = (g == 8) ? out : yexp;
  #pragma unroll
  for (int mi = 0; mi < 4; ++mi) {
    #pragma unroll
    for (int j = 0; j < 4; ++j) {
      int r = wr + mi * 16 + q * 4 + j;
      if (r < rows) {
        int tok = (g == 8) ? (hrow0 + r) : perm[pb + r];
        size_t ob = (size_t)tok * HIDDEN + nbase + wc;
        #pragma unroll
        for (int ni = 0; ni < 4; ++ni)
          dstb[ob + ni * 16 + rl] = acc[mi][ni][j];
      }
    }
  }
}

__global__ void k_add(float* __restrict__ out, const float* __restrict__ yexp, int n4) {
  int i = blockIdx.x * blockDim.x + threadIdx.x;
  if (i >= n4) return;
  float4 a = ((const float4*)out)[i];
  float4 b = ((const float4*)yexp)[i];
  a.x += b.x; a.y += b.y; a.z += b.z; a.w += b.w;
  ((float4*)out)[i] = a;
}

// ---------------- launcher ----------------

extern "C" void kernel_launch(void* const* d_in, const int* in_sizes, int n_in,
                              void* d_out, int out_size, void* d_ws, size_t ws_size,
                              hipStream_t stream) {
  const float* x   = (const float*)d_in[0];
  const float* w1s = (const float*)d_in[1];
  const float* w2s = (const float*)d_in[2];
  const float* w3s = (const float*)d_in[3];
  const float* W1  = (const float*)d_in[4];
  const float* W2  = (const float*)d_in[5];
  const float* W3  = (const float*)d_in[6];
  const float* Wg  = (const float*)d_in[7];
  float* out = (float*)d_out;

  char* ws = (char*)d_ws;
  size_t o_xb   = 0;
  size_t o_H    = o_xb   + (size_t)NTOK * HIDDEN * 2;
  size_t o_yexp = o_H    + (size_t)HROWS * INTER * 2;
  size_t o_idx  = o_yexp + (size_t)NTOK * HIDDEN * 4;
  size_t o_perm = o_idx  + (size_t)NTOK * 4;
  size_t o_cnt  = o_perm + (size_t)NTOK * 4;
  size_t o_off  = o_cnt  + 32;
  size_t o_fill = o_off  + 32;
  size_t o_nblk = o_fill + 32;
  size_t o_tab  = o_nblk + 32;
  size_t need   = o_tab  + (size_t)MAXBLK * 16;
  if (ws_size < need) return;  // insufficient scratch

  u16*  xb   = (u16*)(ws + o_xb);
  u16*  Hbuf = (u16*)(ws + o_H);
  float* yexp = (float*)(ws + o_yexp);
  int*  idx  = (int*)(ws + o_idx);
  int*  perm = (int*)(ws + o_perm);
  int*  cnt  = (int*)(ws + o_cnt);
  int*  off  = (int*)(ws + o_off);
  int*  fill = (int*)(ws + o_fill);
  int*  nblk = (int*)(ws + o_nblk);
  int4* tab  = (int4*)(ws + o_tab);

  k_init<<<1, 64, 0, stream>>>(cnt, fill);
  k_gate<<<NTOK / 4, 256, 0, stream>>>(x, Wg, idx, cnt);
  k_cvt<<<(NTOK * HIDDEN / 4) / 256, 256, 0, stream>>>(x, xb, NTOK * HIDDEN / 4);
  k_table<<<1, 1, 0, stream>>>(cnt, off, tab, nblk);
  k_scatter<<<NTOK / 256, 256, 0, stream>>>(idx, off, fill, perm);
  k_mlp1<<<dim3(MAXBLK, INTER / BN), 256, 0, stream>>>(xb, w1s, w2s, W1, W2, perm, tab, nblk, Hbuf);
  k_mlp2<<<dim3(MAXBLK, HIDDEN / BN), 256, 0, stream>>>(Hbuf, w3s, W3, perm, tab, nblk, out, yexp);
  k_add<<<(NTOK * HIDDEN / 4) / 256, 256, 0, stream>>>(out, yexp, NTOK * HIDDEN / 4);
}

// Round 2
// 672.979 us; speedup vs baseline: 1.3957x; 1.3957x over previous
//
#include <hip/hip_runtime.h>
#include <stdint.h>

#define HIDDEN 1024
#define INTER  4096
#define NTOK   4096
#define HROWS  (2*NTOK)
#define BM     128
#define BN     128
#define BK     64
#define MAXBLK 72
#define NMAT   27            // 0..8: w1s,W1[0..7]; 9..17: w2s,W2; 18..26: w3s,W3
#define TPM    512           // 16KB tiles per matrix

typedef unsigned short u16;
typedef unsigned int   u32;
typedef __bf16  bf16x8 __attribute__((ext_vector_type(8)));
typedef float   f32x4  __attribute__((ext_vector_type(4)));
typedef u32     u32x4  __attribute__((ext_vector_type(4)));

__device__ __forceinline__ u16 f2bf(float f) {
  u32 u = __float_as_uint(f);
  u32 r = u + 0x7FFFu + ((u >> 16) & 1u);
  return (u16)(r >> 16);
}

__device__ __forceinline__ u32 cvt_pk_bf16(float lo, float hi) {
  u32 r;
  asm("v_cvt_pk_bf16_f32 %0, %1, %2" : "=v"(r) : "v"(lo), "v"(hi));
  return r;
}

__device__ __forceinline__ void glds16(const void* g, void* l) {
  __builtin_amdgcn_global_load_lds(
      (const __attribute__((address_space(1))) void*)g,
      (__attribute__((address_space(3))) void*)l, 16, 0, 0);
}

// ---------------- routing ----------------

__global__ void k_init(int* cnt, int* fill) {
  if (threadIdx.x < 8) { cnt[threadIdx.x] = 0; fill[threadIdx.x] = 0; }
}

__global__ __launch_bounds__(256) void k_gate(const float* __restrict__ x,
                                              const float* __restrict__ wg,
                                              int* __restrict__ idx,
                                              int* __restrict__ cnt) {
  int wave = threadIdx.x >> 6, lane = threadIdx.x & 63;
  int t = blockIdx.x * 4 + wave;
  if (t >= NTOK) return;
  float acc[8];
  #pragma unroll
  for (int e = 0; e < 8; ++e) acc[e] = 0.f;
  const float* xr = x + (size_t)t * HIDDEN;
  for (int c = lane; c < HIDDEN; c += 64) {
    float xv = xr[c];
    const float* wrow = wg + (size_t)c * 8;
    #pragma unroll
    for (int e = 0; e < 8; ++e) acc[e] += xv * wrow[e];
  }
  #pragma unroll
  for (int e = 0; e < 8; ++e)
    for (int s = 32; s; s >>= 1) acc[e] += __shfl_xor(acc[e], s);
  if (lane == 0) {
    int best = 0; float bv = acc[0];
    #pragma unroll
    for (int e = 1; e < 8; ++e) if (acc[e] > bv) { bv = acc[e]; best = e; }
    idx[t] = best;
    atomicAdd(&cnt[best], 1);
  }
}

__global__ void k_cvt(const float* __restrict__ x, u16* __restrict__ xb, int n4) {
  int i = blockIdx.x * blockDim.x + threadIdx.x;
  if (i >= n4) return;
  float4 v = ((const float4*)x)[i];
  ushort4 o;
  o.x = f2bf(v.x); o.y = f2bf(v.y); o.z = f2bf(v.z); o.w = f2bf(v.w);
  ((ushort4*)xb)[i] = o;
}

__global__ void k_table(const int* __restrict__ cnt, int* __restrict__ off,
                        int4* __restrict__ tab, int* __restrict__ nblk) {
  if (threadIdx.x != 0 || blockIdx.x != 0) return;
  int o = 0, nb = 0;
  int offs[8];
  for (int e = 0; e < 8; ++e) { offs[e] = o; off[e] = o; o += cnt[e]; }
  for (int m = 0; m < NTOK / BM; ++m)
    tab[nb++] = make_int4(8, m * BM, BM, 0);
  for (int e = 0; e < 8; ++e) {
    for (int j = 0; j * BM < cnt[e]; ++j) {
      int rows = cnt[e] - j * BM; if (rows > BM) rows = BM;
      tab[nb++] = make_int4(e, NTOK + offs[e] + j * BM, rows, offs[e] + j * BM);
    }
  }
  *nblk = nb;
}

__global__ void k_scatter(const int* __restrict__ idx, const int* __restrict__ off,
                          int* __restrict__ fill, int* __restrict__ perm) {
  int t = blockIdx.x * blockDim.x + threadIdx.x;
  if (t >= NTOK) return;
  int e = idx[t];
  int p = atomicAdd(&fill[e], 1);
  perm[off[e] + p] = t;
}

// ---------------- weight precvt: fp32 [K][N] -> bf16 pre-swizzled 16KB panel images ----------------
// Image for panel (matrix m, kt, pp): element (n in [0,128), k in [0,64)) at
// u16 offset n*64 + ((k>>3) ^ (n&7))*8 + (k&7).  Panels stored at Wb + tile*8192,
// tile = m*512 + kt*Tp + pp  (set1/2: Tp=32; set3: Tp=8).

__global__ __launch_bounds__(256) void k_wcvt(
    const float* __restrict__ w1s, const float* __restrict__ w2s,
    const float* __restrict__ w3s, const float* __restrict__ W1,
    const float* __restrict__ W2,  const float* __restrict__ W3,
    u16* __restrict__ Wb)
{
  int bid = blockIdx.x;            // 0 .. NMAT*TPM-1
  int m = bid >> 9;
  int tile = bid & (TPM - 1);
  const float* src; int N, kt, pp;
  if (m < 18) {
    N = INTER;
    int mm = (m < 9) ? m : m - 9;
    const float* sp = (m < 9) ? w1s : w2s;
    const float* ep = (m < 9) ? W1 : W2;
    src = (mm == 0) ? sp : ep + (size_t)(mm - 1) * HIDDEN * INTER;
    kt = tile >> 5; pp = tile & 31;
  } else {
    N = HIDDEN;
    int mm = m - 18;
    src = (mm == 0) ? w3s : W3 + (size_t)(mm - 1) * INTER * HIDDEN;
    kt = tile >> 3; pp = tile & 7;
  }

  __shared__ float tileF[64 * 128];
  int tid = threadIdx.x;
  const float* in0 = src + (size_t)(kt * 64) * N + pp * 128;
  #pragma unroll
  for (int i = 0; i < 8; ++i) {
    int f = tid + 256 * i;          // float4 index within 64x128 tile
    int k = f >> 5, c4 = f & 31;
    *(float4*)&tileF[k * 128 + c4 * 4] = *(const float4*)(in0 + (size_t)k * N + c4 * 4);
  }
  __syncthreads();

  int n = tid >> 1;
  int ph = (tid & 1) * 4;           // chunk-slot half
  u16* outp = Wb + (size_t)bid * 8192 + n * 64 + ph * 8;
  #pragma unroll
  for (int j = 0; j < 4; ++j) {
    int p8 = ph + j;
    int k8 = p8 ^ (n & 7);          // slot p8 holds k-chunk k8
    const float* col = &tileF[(k8 * 8) * 128 + n];
    u32x4 pk;
    pk.x = cvt_pk_bf16(col[0],   col[128]);
    pk.y = cvt_pk_bf16(col[256], col[384]);
    pk.z = cvt_pk_bf16(col[512], col[640]);
    pk.w = cvt_pk_bf16(col[768], col[896]);
    *(u32x4*)(outp + j * 8) = pk;
  }
}

// ---------------- stage 1: H = gelu(Xg@W1) * (Xg@W2), bf16 ----------------

__global__ __launch_bounds__(256) void k_mlp1(
    const u16* __restrict__ xb, const u16* __restrict__ Wb,
    const int* __restrict__ perm, const int4* __restrict__ tab,
    const int* __restrict__ nblk, u16* __restrict__ Hbuf)
{
  int bx = blockIdx.x;
  if (bx >= *nblk) return;
  int4 te = tab[bx];
  int g = te.x, hrow0 = te.y, rows = te.z, pb = te.w;
  int m1 = (g == 8) ? 0 : 1 + g;
  int pp = blockIdx.y;
  int nbase = pp * BN;

  int tid = threadIdx.x;
  int w = tid >> 6, lane = tid & 63;
  int q = lane >> 4, rl = lane & 15;
  int wr = (w >> 1) * 64, wc = (w & 1) * 64;

  __shared__ __align__(16) u16 lA[BM * BK];
  __shared__ __align__(16) u16 lB1[BN * BK];
  __shared__ __align__(16) u16 lB2[BN * BK];

  int tokj[4];
  #pragma unroll
  for (int j = 0; j < 4; ++j) {
    int r = w * 32 + j * 8 + (lane >> 3);
    int rc = (r < rows) ? r : (rows - 1);
    tokj[j] = (g == 8) ? (hrow0 + rc) : perm[pb + rc];
  }
  int schunk = (lane & 7) ^ ((lane >> 3) & 7);

  f32x4 acc1[4][4], acc2[4][4];
  f32x4 z = {0.f, 0.f, 0.f, 0.f};
  #pragma unroll
  for (int mi = 0; mi < 4; ++mi)
    #pragma unroll
    for (int ni = 0; ni < 4; ++ni) { acc1[mi][ni] = z; acc2[mi][ni] = z; }

  const char* pB1 = (const char*)(Wb + ((size_t)m1 * TPM + pp) * 8192);
  const char* pB2 = (const char*)(Wb + ((size_t)(m1 + 9) * TPM + pp) * 8192);

  for (int kt = 0; kt < HIDDEN / BK; ++kt) {
    int k0 = kt * BK;
    #pragma unroll
    for (int j = 0; j < 4; ++j) {
      const char* src = (const char*)xb + ((size_t)tokj[j] * HIDDEN + k0) * 2 + schunk * 16;
      glds16(src, (char*)lA + w * 4096 + j * 1024);
    }
    size_t ko = (size_t)kt * 32 * 16384;   // bytes: kt * Tp(32) * 16KB
    #pragma unroll
    for (int j = 0; j < 4; ++j) {
      int base = w * 4096 + j * 1024;
      glds16(pB1 + ko + base + lane * 16, (char*)lB1 + base);
      glds16(pB2 + ko + base + lane * 16, (char*)lB2 + base);
    }
    __syncthreads();
    #pragma unroll
    for (int ks = 0; ks < 2; ++ks) {
      int co = (((ks << 2) | q) ^ (rl & 7)) * 8;
      bf16x8 af[4], bf1[4], bf2[4];
      #pragma unroll
      for (int mi = 0; mi < 4; ++mi) {
        int r = wr + mi * 16 + rl;
        af[mi] = *(const bf16x8*)&lA[r * BK + co];
      }
      #pragma unroll
      for (int ni = 0; ni < 4; ++ni) {
        int n = wc + ni * 16 + rl;
        bf1[ni] = *(const bf16x8*)&lB1[n * BK + co];
        bf2[ni] = *(const bf16x8*)&lB2[n * BK + co];
      }
      #pragma unroll
      for (int mi = 0; mi < 4; ++mi)
        #pragma unroll
        for (int ni = 0; ni < 4; ++ni) {
          acc1[mi][ni] = __builtin_amdgcn_mfma_f32_16x16x32_bf16(af[mi], bf1[ni], acc1[mi][ni], 0, 0, 0);
          acc2[mi][ni] = __builtin_amdgcn_mfma_f32_16x16x32_bf16(af[mi], bf2[ni], acc2[mi][ni], 0, 0, 0);
        }
    }
    __syncthreads();
  }

  #pragma unroll
  for (int mi = 0; mi < 4; ++mi) {
    #pragma unroll
    for (int j = 0; j < 4; ++j) {
      int r = wr + mi * 16 + q * 4 + j;
      if (r < rows) {
        size_t hb = (size_t)(hrow0 + r) * INTER + nbase + wc;
        #pragma unroll
        for (int ni = 0; ni < 4; ++ni) {
          float h1 = acc1[mi][ni][j];
          float h2 = acc2[mi][ni][j];
          float ge = 0.5f * h1 * (1.0f + erff(h1 * 0.7071067811865476f));
          Hbuf[hb + ni * 16 + rl] = f2bf(ge * h2);
        }
      }
    }
  }
}

// ---------------- stage 2: Y = H @ W3 ----------------

__global__ __launch_bounds__(256) void k_mlp2(
    const u16* __restrict__ Hbuf, const u16* __restrict__ Wb,
    const int* __restrict__ perm, const int4* __restrict__ tab,
    const int* __restrict__ nblk, float* __restrict__ out,
    float* __restrict__ yexp)
{
  int bx = blockIdx.x;
  if (bx >= *nblk) return;
  int4 te = tab[bx];
  int g = te.x, hrow0 = te.y, rows = te.z, pb = te.w;
  int m3 = (g == 8) ? 18 : 19 + g;
  int pp = blockIdx.y;
  int nbase = pp * BN;

  int tid = threadIdx.x;
  int w = tid >> 6, lane = tid & 63;
  int q = lane >> 4, rl = lane & 15;
  int wr = (w >> 1) * 64, wc = (w & 1) * 64;

  __shared__ __align__(16) u16 lA[BM * BK];
  __shared__ __align__(16) u16 lB[BN * BK];

  int hr[4];
  #pragma unroll
  for (int j = 0; j < 4; ++j) {
    int r = w * 32 + j * 8 + (lane >> 3);
    int rc = (r < rows) ? r : (rows - 1);
    hr[j] = hrow0 + rc;
  }
  int schunk = (lane & 7) ^ ((lane >> 3) & 7);

  f32x4 acc[4][4];
  f32x4 z = {0.f, 0.f, 0.f, 0.f};
  #pragma unroll
  for (int mi = 0; mi < 4; ++mi)
    #pragma unroll
    for (int ni = 0; ni < 4; ++ni) acc[mi][ni] = z;

  const char* pB = (const char*)(Wb + ((size_t)m3 * TPM + pp) * 8192);

  for (int kt = 0; kt < INTER / BK; ++kt) {
    int k0 = kt * BK;
    #pragma unroll
    for (int j = 0; j < 4; ++j) {
      const char* src = (const char*)Hbuf + ((size_t)hr[j] * INTER + k0) * 2 + schunk * 16;
      glds16(src, (char*)lA + w * 4096 + j * 1024);
    }
    size_t ko = (size_t)kt * 8 * 16384;    // bytes: kt * Tp(8) * 16KB
    #pragma unroll
    for (int j = 0; j < 4; ++j) {
      int base = w * 4096 + j * 1024;
      glds16(pB + ko + base + lane * 16, (char*)lB + base);
    }
    __syncthreads();
    #pragma unroll
    for (int ks = 0; ks < 2; ++ks) {
      int co = (((ks << 2) | q) ^ (rl & 7)) * 8;
      bf16x8 af[4], bf[4];
      #pragma unroll
      for (int mi = 0; mi < 4; ++mi) {
        int r = wr + mi * 16 + rl;
        af[mi] = *(const bf16x8*)&lA[r * BK + co];
      }
      #pragma unroll
      for (int ni = 0; ni < 4; ++ni) {
        int n = wc + ni * 16 + rl;
        bf[ni] = *(const bf16x8*)&lB[n * BK + co];
      }
      #pragma unroll
      for (int mi = 0; mi < 4; ++mi)
        #pragma unroll
        for (int ni = 0; ni < 4; ++ni)
          acc[mi][ni] = __builtin_amdgcn_mfma_f32_16x16x32_bf16(af[mi], bf[ni], acc[mi][ni], 0, 0, 0);
    }
    __syncthreads();
  }

  float* dstb = (g == 8) ? out : yexp;
  #pragma unroll
  for (int mi = 0; mi < 4; ++mi) {
    #pragma unroll
    for (int j = 0; j < 4; ++j) {
      int r = wr + mi * 16 + q * 4 + j;
      if (r < rows) {
        int tok = (g == 8) ? (hrow0 + r) : perm[pb + r];
        size_t ob = (size_t)tok * HIDDEN + nbase + wc;
        #pragma unroll
        for (int ni = 0; ni < 4; ++ni)
          dstb[ob + ni * 16 + rl] = acc[mi][ni][j];
      }
    }
  }
}

__global__ void k_add(float* __restrict__ out, const float* __restrict__ yexp, int n4) {
  int i = blockIdx.x * blockDim.x + threadIdx.x;
  if (i >= n4) return;
  float4 a = ((const float4*)out)[i];
  float4 b = ((const float4*)yexp)[i];
  a.x += b.x; a.y += b.y; a.z += b.z; a.w += b.w;
  ((float4*)out)[i] = a;
}

// ---------------- launcher ----------------

extern "C" void kernel_launch(void* const* d_in, const int* in_sizes, int n_in,
                              void* d_out, int out_size, void* d_ws, size_t ws_size,
                              hipStream_t stream) {
  const float* x   = (const float*)d_in[0];
  const float* w1s = (const float*)d_in[1];
  const float* w2s = (const float*)d_in[2];
  const float* w3s = (const float*)d_in[3];
  const float* W1  = (const float*)d_in[4];
  const float* W2  = (const float*)d_in[5];
  const float* W3  = (const float*)d_in[6];
  const float* Wg  = (const float*)d_in[7];
  float* out = (float*)d_out;

  char* ws = (char*)d_ws;
  size_t o_xb   = 0;
  size_t o_H    = o_xb   + (size_t)NTOK * HIDDEN * 2;           // 8 MB
  size_t o_yexp = o_H    + (size_t)HROWS * INTER * 2;           // +64 MB
  size_t o_Wb   = o_yexp + (size_t)NTOK * HIDDEN * 4;           // +16 MB
  size_t o_idx  = o_Wb   + (size_t)NMAT * TPM * 16384;          // +216 MB
  size_t o_perm = o_idx  + (size_t)NTOK * 4;
  size_t o_cnt  = o_perm + (size_t)NTOK * 4;
  size_t o_off  = o_cnt  + 32;
  size_t o_fill = o_off  + 32;
  size_t o_nblk = o_fill + 32;
  size_t o_tab  = o_nblk + 32;
  size_t need   = o_tab  + (size_t)MAXBLK * 16;
  if (ws_size < need) return;  // insufficient scratch

  u16*  xb   = (u16*)(ws + o_xb);
  u16*  Hbuf = (u16*)(ws + o_H);
  float* yexp = (float*)(ws + o_yexp);
  u16*  Wb   = (u16*)(ws + o_Wb);
  int*  idx  = (int*)(ws + o_idx);
  int*  perm = (int*)(ws + o_perm);
  int*  cnt  = (int*)(ws + o_cnt);
  int*  off  = (int*)(ws + o_off);
  int*  fill = (int*)(ws + o_fill);
  int*  nblk = (int*)(ws + o_nblk);
  int4* tab  = (int4*)(ws + o_tab);

  k_init<<<1, 64, 0, stream>>>(cnt, fill);
  k_gate<<<NTOK / 4, 256, 0, stream>>>(x, Wg, idx, cnt);
  k_cvt<<<(NTOK * HIDDEN / 4) / 256, 256, 0, stream>>>(x, xb, NTOK * HIDDEN / 4);
  k_wcvt<<<NMAT * TPM, 256, 0, stream>>>(w1s, w2s, w3s, W1, W2, W3, Wb);
  k_table<<<1, 1, 0, stream>>>(cnt, off, tab, nblk);
  k_scatter<<<NTOK / 256, 256, 0, stream>>>(idx, off, fill, perm);
  k_mlp1<<<dim3(MAXBLK, INTER / BN), 256, 0, stream>>>(xb, Wb, perm, tab, nblk, Hbuf);
  k_mlp2<<<dim3(MAXBLK, HIDDEN / BN), 256, 0, stream>>>(Hbuf, Wb, perm, tab, nblk, out, yexp);
  k_add<<<(NTOK * HIDDEN / 4) / 256, 256, 0, stream>>>(out, yexp, NTOK * HIDDEN / 4);
}

// Round 3
// 539.802 us; speedup vs baseline: 1.7401x; 1.2467x over previous
//
#include <hip/hip_runtime.h>
#include <stdint.h>

#define HIDDEN 1024
#define INTER  4096
#define NTOK   4096
#define HROWS  (2*NTOK)
#define BK     64
#define MAXB1  40            // 256-row-granularity table (mlp1)
#define MAXB2  72            // 128-row-granularity table (mlp2)
#define NMAT   27            // 0..8: w1s,W1[0..7]; 9..17: w2s,W2; 18..26: w3s,W3
#define TPM    512           // 16KB tiles per matrix

typedef unsigned short u16;
typedef unsigned int   u32;
typedef __bf16  bf16x8 __attribute__((ext_vector_type(8)));
typedef float   f32x4  __attribute__((ext_vector_type(4)));
typedef u32     u32x4  __attribute__((ext_vector_type(4)));

__device__ __forceinline__ u16 f2bf(float f) {
  u32 u = __float_as_uint(f);
  u32 r = u + 0x7FFFu + ((u >> 16) & 1u);
  return (u16)(r >> 16);
}

__device__ __forceinline__ u32 cvt_pk_bf16(float lo, float hi) {
  u32 r;
  asm("v_cvt_pk_bf16_f32 %0, %1, %2" : "=v"(r) : "v"(lo), "v"(hi));
  return r;
}

__device__ __forceinline__ void glds16(const void* g, void* l) {
  __builtin_amdgcn_global_load_lds(
      (const __attribute__((address_space(1))) void*)g,
      (__attribute__((address_space(3))) void*)l, 16, 0, 0);
}

// ---------------- routing ----------------

__global__ void k_init(int* cnt, int* fill) {
  if (threadIdx.x < 8) { cnt[threadIdx.x] = 0; fill[threadIdx.x] = 0; }
}

__global__ __launch_bounds__(256) void k_gate(const float* __restrict__ x,
                                              const float* __restrict__ wg,
                                              int* __restrict__ idx,
                                              int* __restrict__ cnt) {
  int wave = threadIdx.x >> 6, lane = threadIdx.x & 63;
  int t = blockIdx.x * 4 + wave;
  if (t >= NTOK) return;
  float acc[8];
  #pragma unroll
  for (int e = 0; e < 8; ++e) acc[e] = 0.f;
  const float* xr = x + (size_t)t * HIDDEN;
  for (int c = lane; c < HIDDEN; c += 64) {
    float xv = xr[c];
    const float* wrow = wg + (size_t)c * 8;
    #pragma unroll
    for (int e = 0; e < 8; ++e) acc[e] += xv * wrow[e];
  }
  #pragma unroll
  for (int e = 0; e < 8; ++e)
    for (int s = 32; s; s >>= 1) acc[e] += __shfl_xor(acc[e], s);
  if (lane == 0) {
    int best = 0; float bv = acc[0];
    #pragma unroll
    for (int e = 1; e < 8; ++e) if (acc[e] > bv) { bv = acc[e]; best = e; }
    idx[t] = best;
    atomicAdd(&cnt[best], 1);
  }
}

__global__ void k_cvt(const float* __restrict__ x, u16* __restrict__ xb, int n4) {
  int i = blockIdx.x * blockDim.x + threadIdx.x;
  if (i >= n4) return;
  float4 v = ((const float4*)x)[i];
  ushort4 o;
  o.x = f2bf(v.x); o.y = f2bf(v.y); o.z = f2bf(v.z); o.w = f2bf(v.w);
  ((ushort4*)xb)[i] = o;
}

__global__ void k_table(const int* __restrict__ cnt, int* __restrict__ off,
                        int4* __restrict__ tab1, int* __restrict__ nblk1,
                        int4* __restrict__ tab2, int* __restrict__ nblk2) {
  if (threadIdx.x != 0 || blockIdx.x != 0) return;
  int o = 0;
  int offs[8];
  for (int e = 0; e < 8; ++e) { offs[e] = o; off[e] = o; o += cnt[e]; }
  int nb = 0;
  for (int m = 0; m < NTOK / 256; ++m)
    tab1[nb++] = make_int4(8, m * 256, 256, 0);
  for (int e = 0; e < 8; ++e)
    for (int j = 0; j * 256 < cnt[e]; ++j) {
      int rows = cnt[e] - j * 256; if (rows > 256) rows = 256;
      tab1[nb++] = make_int4(e, NTOK + offs[e] + j * 256, rows, offs[e] + j * 256);
    }
  *nblk1 = nb;
  nb = 0;
  for (int m = 0; m < NTOK / 128; ++m)
    tab2[nb++] = make_int4(8, m * 128, 128, 0);
  for (int e = 0; e < 8; ++e)
    for (int j = 0; j * 128 < cnt[e]; ++j) {
      int rows = cnt[e] - j * 128; if (rows > 128) rows = 128;
      tab2[nb++] = make_int4(e, NTOK + offs[e] + j * 128, rows, offs[e] + j * 128);
    }
  *nblk2 = nb;
}

__global__ void k_scatter(const int* __restrict__ idx, const int* __restrict__ off,
                          int* __restrict__ fill, int* __restrict__ perm) {
  int t = blockIdx.x * blockDim.x + threadIdx.x;
  if (t >= NTOK) return;
  int e = idx[t];
  int p = atomicAdd(&fill[e], 1);
  perm[off[e] + p] = t;
}

// ---------------- weight precvt: fp32 [K][N] -> bf16 pre-swizzled 16KB panel images ----------------
// Panel (matrix m, kt, pp): element (n in [0,128), k in [0,64)) at u16 offset
// n*64 + ((k>>3) ^ (n&7))*8 + (k&7).  tile = m*512 + kt*Tp + pp (w1/w2: Tp=32; w3: Tp=8).

__global__ __launch_bounds__(256) void k_wcvt(
    const float* __restrict__ w1s, const float* __restrict__ w2s,
    const float* __restrict__ w3s, const float* __restrict__ W1,
    const float* __restrict__ W2,  const float* __restrict__ W3,
    u16* __restrict__ Wb)
{
  int bid = blockIdx.x;
  int m = bid >> 9;
  int tile = bid & (TPM - 1);
  const float* src; int N, kt, pp;
  if (m < 18) {
    N = INTER;
    int mm = (m < 9) ? m : m - 9;
    const float* sp = (m < 9) ? w1s : w2s;
    const float* ep = (m < 9) ? W1 : W2;
    src = (mm == 0) ? sp : ep + (size_t)(mm - 1) * HIDDEN * INTER;
    kt = tile >> 5; pp = tile & 31;
  } else {
    N = HIDDEN;
    int mm = m - 18;
    src = (mm == 0) ? w3s : W3 + (size_t)(mm - 1) * INTER * HIDDEN;
    kt = tile >> 3; pp = tile & 7;
  }

  __shared__ float tileF[64 * 128];
  int tid = threadIdx.x;
  const float* in0 = src + (size_t)(kt * 64) * N + pp * 128;
  #pragma unroll
  for (int i = 0; i < 8; ++i) {
    int f = tid + 256 * i;
    int k = f >> 5, c4 = f & 31;
    *(float4*)&tileF[k * 128 + c4 * 4] = *(const float4*)(in0 + (size_t)k * N + c4 * 4);
  }
  __syncthreads();

  int n = tid >> 1;
  int ph = (tid & 1) * 4;
  u16* outp = Wb + (size_t)bid * 8192 + n * 64 + ph * 8;
  #pragma unroll
  for (int j = 0; j < 4; ++j) {
    int p8 = ph + j;
    int k8 = p8 ^ (n & 7);
    const float* col = &tileF[(k8 * 8) * 128 + n];
    u32x4 pk;
    pk.x = cvt_pk_bf16(col[0],   col[128]);
    pk.y = cvt_pk_bf16(col[256], col[384]);
    pk.z = cvt_pk_bf16(col[512], col[640]);
    pk.w = cvt_pk_bf16(col[768], col[896]);
    *(u32x4*)(outp + j * 8) = pk;
  }
}

// ---------------- stage 1: H = gelu(Xg@W1) * (Xg@W2) ----------------
// 256x(128 dual) tile, 8 waves (2M x 4N), BK=64, double-buffered 2-phase.
// LDS per buffer (bytes): A [0,32768), B1 [32768,49152), B2 [49152,65536).

__global__ __launch_bounds__(512, 2) void k_mlp1(
    const u16* __restrict__ xb, const u16* __restrict__ Wb,
    const int* __restrict__ perm, const int4* __restrict__ tab,
    const int* __restrict__ nblk, u16* __restrict__ Hbuf)
{
  int bx = blockIdx.x;
  if (bx >= *nblk) return;
  int4 te = tab[bx];
  int g = te.x, hrow0 = te.y, rows = te.z, pb = te.w;
  int m1 = (g == 8) ? 0 : 1 + g;
  int pp = blockIdx.y;
  int nbase = pp * 128;

  extern __shared__ __align__(16) char smem[];
  int tid = threadIdx.x;
  int w = tid >> 6, lane = tid & 63;
  int q = lane >> 4, rl = lane & 15;
  int mw = w >> 2, nw = w & 3;

  int tokj[4];
  #pragma unroll
  for (int j = 0; j < 4; ++j) {
    int r = w * 32 + j * 8 + (lane >> 3);
    int rc = (r < rows) ? r : (rows - 1);
    tokj[j] = (g == 8) ? (hrow0 + rc) : perm[pb + rc];
  }
  int schunk = (lane & 7) ^ ((lane >> 3) & 7);

  const char* pB1 = (const char*)(Wb + ((size_t)m1 * TPM + pp) * 8192);
  const char* pB2 = (const char*)(Wb + ((size_t)(m1 + 9) * TPM + pp) * 8192);

  f32x4 acc1[8][2], acc2[8][2];
  f32x4 z = {0.f, 0.f, 0.f, 0.f};
  #pragma unroll
  for (int mi = 0; mi < 8; ++mi)
    #pragma unroll
    for (int ni = 0; ni < 2; ++ni) { acc1[mi][ni] = z; acc2[mi][ni] = z; }

  auto STAGE = [&](char* L, int kt) {
    int k0 = kt * BK;
    #pragma unroll
    for (int j = 0; j < 4; ++j) {
      const char* src = (const char*)xb + ((size_t)tokj[j] * HIDDEN + k0) * 2 + schunk * 16;
      glds16(src, L + w * 4096 + j * 1024);
    }
    size_t ko = (size_t)kt * 32 * 16384;
    #pragma unroll
    for (int j = 0; j < 2; ++j) {
      int o = w * 2048 + j * 1024;
      glds16(pB1 + ko + o + lane * 16, L + 32768 + o);
      glds16(pB2 + ko + o + lane * 16, L + 49152 + o);
    }
  };

  auto COMPUTE = [&](const char* Lc) {
    const u16* LA  = (const u16*)Lc;
    const u16* LB1 = (const u16*)(Lc + 32768);
    const u16* LB2 = (const u16*)(Lc + 49152);
    #pragma unroll
    for (int ks = 0; ks < 2; ++ks) {
      int co = (((ks << 2) | q) ^ (rl & 7)) * 8;
      bf16x8 af[8], b1[2], b2[2];
      #pragma unroll
      for (int mi = 0; mi < 8; ++mi)
        af[mi] = *(const bf16x8*)&LA[(mw * 128 + mi * 16 + rl) * 64 + co];
      #pragma unroll
      for (int ni = 0; ni < 2; ++ni) {
        int n = nw * 32 + ni * 16 + rl;
        b1[ni] = *(const bf16x8*)&LB1[n * 64 + co];
        b2[ni] = *(const bf16x8*)&LB2[n * 64 + co];
      }
      #pragma unroll
      for (int mi = 0; mi < 8; ++mi)
        #pragma unroll
        for (int ni = 0; ni < 2; ++ni) {
          acc1[mi][ni] = __builtin_amdgcn_mfma_f32_16x16x32_bf16(af[mi], b1[ni], acc1[mi][ni], 0, 0, 0);
          acc2[mi][ni] = __builtin_amdgcn_mfma_f32_16x16x32_bf16(af[mi], b2[ni], acc2[mi][ni], 0, 0, 0);
        }
    }
  };

  char* L0 = smem;
  char* L1 = smem + 65536;
  STAGE(L0, 0);
  asm volatile("s_waitcnt vmcnt(0)" ::: "memory");
  __syncthreads();
  int cur = 0;
  for (int kt = 0; kt < HIDDEN / BK; ++kt) {
    char* Lc = cur ? L1 : L0;
    char* Ln = cur ? L0 : L1;
    if (kt < HIDDEN / BK - 1) STAGE(Ln, kt + 1);
    COMPUTE(Lc);
    if (kt < HIDDEN / BK - 1) {
      asm volatile("s_waitcnt vmcnt(0)" ::: "memory");
      __syncthreads();
      cur ^= 1;
    }
  }

  #pragma unroll
  for (int mi = 0; mi < 8; ++mi) {
    #pragma unroll
    for (int j = 0; j < 4; ++j) {
      int r = mw * 128 + mi * 16 + q * 4 + j;
      if (r < rows) {
        size_t hb = (size_t)(hrow0 + r) * INTER + nbase + nw * 32;
        #pragma unroll
        for (int ni = 0; ni < 2; ++ni) {
          float h1 = acc1[mi][ni][j];
          float h2 = acc2[mi][ni][j];
          float ge = 0.5f * h1 * (1.0f + erff(h1 * 0.7071067811865476f));
          Hbuf[hb + ni * 16 + rl] = f2bf(ge * h2);
        }
      }
    }
  }
}

// ---------------- stage 2: Y = H @ W3 ----------------
// 128x128 tile, 4 waves, BK=64, double-buffered 2-phase.
// LDS per buffer (bytes): A [0,16384), B [16384,32768).

__global__ __launch_bounds__(256, 2) void k_mlp2(
    const u16* __restrict__ Hbuf, const u16* __restrict__ Wb,
    const int* __restrict__ perm, const int4* __restrict__ tab,
    const int* __restrict__ nblk, float* __restrict__ out,
    float* __restrict__ yexp)
{
  int bx = blockIdx.x;
  if (bx >= *nblk) return;
  int4 te = tab[bx];
  int g = te.x, hrow0 = te.y, rows = te.z, pb = te.w;
  int m3 = (g == 8) ? 18 : 19 + g;
  int pp = blockIdx.y;
  int nbase = pp * 128;

  extern __shared__ __align__(16) char smem[];
  int tid = threadIdx.x;
  int w = tid >> 6, lane = tid & 63;
  int q = lane >> 4, rl = lane & 15;
  int wr = (w >> 1) * 64, wc = (w & 1) * 64;

  int hr[4];
  #pragma unroll
  for (int j = 0; j < 4; ++j) {
    int r = w * 32 + j * 8 + (lane >> 3);
    int rc = (r < rows) ? r : (rows - 1);
    hr[j] = hrow0 + rc;
  }
  int schunk = (lane & 7) ^ ((lane >> 3) & 7);

  const char* pB = (const char*)(Wb + ((size_t)m3 * TPM + pp) * 8192);

  f32x4 acc[4][4];
  f32x4 z = {0.f, 0.f, 0.f, 0.f};
  #pragma unroll
  for (int mi = 0; mi < 4; ++mi)
    #pragma unroll
    for (int ni = 0; ni < 4; ++ni) acc[mi][ni] = z;

  auto STAGE = [&](char* L, int kt) {
    int k0 = kt * BK;
    #pragma unroll
    for (int j = 0; j < 4; ++j) {
      const char* src = (const char*)Hbuf + ((size_t)hr[j] * INTER + k0) * 2 + schunk * 16;
      glds16(src, L + w * 4096 + j * 1024);
    }
    size_t ko = (size_t)kt * 8 * 16384;
    #pragma unroll
    for (int j = 0; j < 4; ++j) {
      int o = w * 4096 + j * 1024;
      glds16(pB + ko + o + lane * 16, L + 16384 + o);
    }
  };

  auto COMPUTE = [&](const char* Lc) {
    const u16* LA = (const u16*)Lc;
    const u16* LB = (const u16*)(Lc + 16384);
    #pragma unroll
    for (int ks = 0; ks < 2; ++ks) {
      int co = (((ks << 2) | q) ^ (rl & 7)) * 8;
      bf16x8 af[4], bf[4];
      #pragma unroll
      for (int mi = 0; mi < 4; ++mi)
        af[mi] = *(const bf16x8*)&LA[(wr + mi * 16 + rl) * 64 + co];
      #pragma unroll
      for (int ni = 0; ni < 4; ++ni)
        bf[ni] = *(const bf16x8*)&LB[(wc + ni * 16 + rl) * 64 + co];
      #pragma unroll
      for (int mi = 0; mi < 4; ++mi)
        #pragma unroll
        for (int ni = 0; ni < 4; ++ni)
          acc[mi][ni] = __builtin_amdgcn_mfma_f32_16x16x32_bf16(af[mi], bf[ni], acc[mi][ni], 0, 0, 0);
    }
  };

  char* L0 = smem;
  char* L1 = smem + 32768;
  STAGE(L0, 0);
  asm volatile("s_waitcnt vmcnt(0)" ::: "memory");
  __syncthreads();
  int cur = 0;
  for (int kt = 0; kt < INTER / BK; ++kt) {
    char* Lc = cur ? L1 : L0;
    char* Ln = cur ? L0 : L1;
    if (kt < INTER / BK - 1) STAGE(Ln, kt + 1);
    COMPUTE(Lc);
    if (kt < INTER / BK - 1) {
      asm volatile("s_waitcnt vmcnt(0)" ::: "memory");
      __syncthreads();
      cur ^= 1;
    }
  }

  float* dstb = (g == 8) ? out : yexp;
  #pragma unroll
  for (int mi = 0; mi < 4; ++mi) {
    #pragma unroll
    for (int j = 0; j < 4; ++j) {
      int r = wr + mi * 16 + q * 4 + j;
      if (r < rows) {
        int tok = (g == 8) ? (hrow0 + r) : perm[pb + r];
        size_t ob = (size_t)tok * HIDDEN + nbase + wc;
        #pragma unroll
        for (int ni = 0; ni < 4; ++ni)
          dstb[ob + ni * 16 + rl] = acc[mi][ni][j];
      }
    }
  }
}

__global__ void k_add(float* __restrict__ out, const float* __restrict__ yexp, int n4) {
  int i = blockIdx.x * blockDim.x + threadIdx.x;
  if (i >= n4) return;
  float4 a = ((const float4*)out)[i];
  float4 b = ((const float4*)yexp)[i];
  a.x += b.x; a.y += b.y; a.z += b.z; a.w += b.w;
  ((float4*)out)[i] = a;
}

// ---------------- launcher ----------------

extern "C" void kernel_launch(void* const* d_in, const int* in_sizes, int n_in,
                              void* d_out, int out_size, void* d_ws, size_t ws_size,
                              hipStream_t stream) {
  const float* x   = (const float*)d_in[0];
  const float* w1s = (const float*)d_in[1];
  const float* w2s = (const float*)d_in[2];
  const float* w3s = (const float*)d_in[3];
  const float* W1  = (const float*)d_in[4];
  const float* W2  = (const float*)d_in[5];
  const float* W3  = (const float*)d_in[6];
  const float* Wg  = (const float*)d_in[7];
  float* out = (float*)d_out;

  char* ws = (char*)d_ws;
  size_t o_xb   = 0;
  size_t o_H    = o_xb   + (size_t)NTOK * HIDDEN * 2;           // 8 MB
  size_t o_yexp = o_H    + (size_t)HROWS * INTER * 2;           // +64 MB
  size_t o_Wb   = o_yexp + (size_t)NTOK * HIDDEN * 4;           // +16 MB
  size_t o_idx  = o_Wb   + (size_t)NMAT * TPM * 16384;          // +216 MB
  size_t o_perm = o_idx  + (size_t)NTOK * 4;
  size_t o_cnt  = o_perm + (size_t)NTOK * 4;
  size_t o_off  = o_cnt  + 32;
  size_t o_fill = o_off  + 32;
  size_t o_nb1  = o_fill + 32;
  size_t o_nb2  = o_nb1  + 32;
  size_t o_tab1 = o_nb2  + 32;
  size_t o_tab2 = o_tab1 + (size_t)MAXB1 * 16;
  size_t need   = o_tab2 + (size_t)MAXB2 * 16;
  if (ws_size < need) return;  // insufficient scratch

  u16*  xb   = (u16*)(ws + o_xb);
  u16*  Hbuf = (u16*)(ws + o_H);
  float* yexp = (float*)(ws + o_yexp);
  u16*  Wb   = (u16*)(ws + o_Wb);
  int*  idx  = (int*)(ws + o_idx);
  int*  perm = (int*)(ws + o_perm);
  int*  cnt  = (int*)(ws + o_cnt);
  int*  off  = (int*)(ws + o_off);
  int*  fill = (int*)(ws + o_fill);
  int*  nblk1 = (int*)(ws + o_nb1);
  int*  nblk2 = (int*)(ws + o_nb2);
  int4* tab1 = (int4*)(ws + o_tab1);
  int4* tab2 = (int4*)(ws + o_tab2);

  k_init<<<1, 64, 0, stream>>>(cnt, fill);
  k_gate<<<NTOK / 4, 256, 0, stream>>>(x, Wg, idx, cnt);
  k_cvt<<<(NTOK * HIDDEN / 4) / 256, 256, 0, stream>>>(x, xb, NTOK * HIDDEN / 4);
  k_wcvt<<<NMAT * TPM, 256, 0, stream>>>(w1s, w2s, w3s, W1, W2, W3, Wb);
  k_table<<<1, 1, 0, stream>>>(cnt, off, tab1, nblk1, tab2, nblk2);
  k_scatter<<<NTOK / 256, 256, 0, stream>>>(idx, off, fill, perm);
  k_mlp1<<<dim3(MAXB1, INTER / 128), 512, 131072, stream>>>(xb, Wb, perm, tab1, nblk1, Hbuf);
  k_mlp2<<<dim3(MAXB2, HIDDEN / 128), 256, 65536, stream>>>(Hbuf, Wb, perm, tab2, nblk2, out, yexp);
  k_add<<<(NTOK * HIDDEN / 4) / 256, 256, 0, stream>>>(out, yexp, NTOK * HIDDEN / 4);
}